// Round 1
// 243.860 us; speedup vs baseline: 1.0038x; 1.0038x over previous
//
#include <hip/hip_runtime.h>
#include <hip/hip_bf16.h>

#define NN 1024
#define IN_CH 128
#define EDGE_CH 32
#define OUT_CH 128

typedef __attribute__((ext_vector_type(8))) short bf16x8;
typedef __attribute__((ext_vector_type(4))) float f32x4;

// round-to-nearest-even float -> bf16 (bit trick)
static __device__ __forceinline__ short f2bf(float f) {
    union { float f; unsigned u; } v; v.f = f;
    unsigned r = v.u + 0x7FFFu + ((v.u >> 16) & 1u);
    return (short)(r >> 16);
}

// ---------------------------------------------------------------------------
// Kernel A: P = node_mat @ node_weight (stored TRANSPOSED, bf16: PT[o][m]),
//           R = node_mat @ root (fp32).
// grid 512 x 256: block = 2 node-rows, thread (h = tid>>7) owns one row,
// o = tid & 127. node_weight/root columns are L1/L2-cached across blocks.
// ---------------------------------------------------------------------------
__global__ void node_gemm_kernel(const float* __restrict__ node_mat,
                                 const float* __restrict__ node_weight,
                                 const float* __restrict__ root,
                                 short* __restrict__ PT,
                                 float* __restrict__ R) {
    __shared__ float nm[2 * IN_CH];
    int tid = threadIdx.x;
    int n0 = blockIdx.x * 2;
    nm[tid] = node_mat[n0 * IN_CH + tid];
    __syncthreads();
    int o = tid & 127;
    int h = tid >> 7;
    const float* nr = &nm[h * IN_CH];
    float accp = 0.f, accr = 0.f;
#pragma unroll 8
    for (int c = 0; c < IN_CH; ++c) {
        float x = nr[c];
        accp += x * node_weight[c * OUT_CH + o];
        accr += x * root[c * OUT_CH + o];
    }
    R[(size_t)(n0 + h) * OUT_CH + o] = accr;
    PT[(size_t)o * NN + (n0 + h)] = f2bf(accp);  // transposed bf16 store
}

// ---------------------------------------------------------------------------
// Kernel B (heavy): per node n,
//   G[b]   = sum_m adj[n,m] * relu( sum_e edge_adj[e,n,m] * L1[e,b] )
//   out[n,o] = sum_{b<127} G[b]*L2[b,o] + R[n,o] + bias[o]
// One block (4 waves) per n. MFMA 16x16x32 bf16, K=32 = EDGE_CH exactly.
// A-frag: lane holds A[row=lane&15][k=quad*8+j]; B-frag: B[k=quad*8+j][col=lane&15];
// D: row=quad*4+r, col=lane&15.  (layouts verified by round-1 pass)
// m-loop unrolled x4: 36 independent global loads in flight per wave -> MLP.
// ---------------------------------------------------------------------------
__global__ void edge_out_kernel(const float* __restrict__ edge_adj,
                                const float* __restrict__ adj,
                                const float* __restrict__ L1,
                                const float* __restrict__ L2,
                                const float* __restrict__ R,
                                const float* __restrict__ bias,
                                float* __restrict__ out) {
    int n = blockIdx.x;
    int tid = threadIdx.x;
    int wave = tid >> 6;
    int lane = tid & 63;
    int quad = lane >> 4;
    int col  = lane & 15;

    // Preload constant A fragments: 8 b-tiles of L1^T [b=bt*16+col][e=quad*8+j]
    bf16x8 a_frag[8];
#pragma unroll
    for (int bt = 0; bt < 8; ++bt) {
        int b = bt * 16 + col;
#pragma unroll
        for (int j = 0; j < 8; ++j) {
            int e = quad * 8 + j;
            float v = (b < OUT_CH - 1) ? L1[e * (OUT_CH - 1) + b] : 0.0f;  // pad b=127
            a_frag[bt][j] = f2bf(v);
        }
    }

    float g_acc[8][4];
#pragma unroll
    for (int bt = 0; bt < 8; ++bt)
#pragma unroll
        for (int r = 0; r < 4; ++r) g_acc[bt][r] = 0.0f;

    const float* adj_row = adj + (size_t)n * NN;
    const float* ea_base = edge_adj + (size_t)n * NN;   // + e*NN*NN + m

    // wave w owns m in [w*256, w*256+256), processed as 4 chunks of 64 m,
    // each chunk = 4 sub-tiles of 16 m. All 36 loads of a chunk are issued
    // before the MFMA block (independent).
    for (int c = 0; c < 4; ++c) {
        int base = wave * 256 + c * 64;
        float adjv[4];
        bf16x8 bf[4];
#pragma unroll
        for (int s = 0; s < 4; ++s) {
            int m = base + s * 16 + col;
            adjv[s] = adj_row[m];
#pragma unroll
            for (int j = 0; j < 8; ++j) {
                size_t e = (size_t)(quad * 8 + j);
                bf[s][j] = f2bf(ea_base[e * (size_t)(NN * NN) + m]);
            }
        }
#pragma unroll
        for (int s = 0; s < 4; ++s) {
#pragma unroll
            for (int bt = 0; bt < 8; ++bt) {
                f32x4 d = __builtin_amdgcn_mfma_f32_16x16x32_bf16(
                    a_frag[bt], bf[s], (f32x4){0.f, 0.f, 0.f, 0.f}, 0, 0, 0);
#pragma unroll
                for (int r = 0; r < 4; ++r)
                    g_acc[bt][r] += fmaxf(d[r], 0.0f) * adjv[s];
            }
        }
    }

    // reduce over the 16 column-lanes of each quad (sum over this lane's m's)
#pragma unroll
    for (int bt = 0; bt < 8; ++bt)
#pragma unroll
        for (int r = 0; r < 4; ++r) {
            float v = g_acc[bt][r];
            v += __shfl_xor(v, 1);
            v += __shfl_xor(v, 2);
            v += __shfl_xor(v, 4);
            v += __shfl_xor(v, 8);
            g_acc[bt][r] = v;
        }

    __shared__ float gred[4][OUT_CH];
    __shared__ float gs[OUT_CH];
    __shared__ float part[2][OUT_CH];
    if (col == 0) {
#pragma unroll
        for (int bt = 0; bt < 8; ++bt)
#pragma unroll
            for (int r = 0; r < 4; ++r)
                gred[wave][bt * 16 + quad * 4 + r] = g_acc[bt][r];
    }
    __syncthreads();
    if (tid < OUT_CH)
        gs[tid] = gred[0][tid] + gred[1][tid] + gred[2][tid] + gred[3][tid];
    __syncthreads();

    // epilogue: out[n,o] = sum_{b<127} gs[b]*L2[b,o] + R[n,o] + bias[o]
    int o = tid & 127;
    int hf = tid >> 7;
    float acc = 0.f;
    int blo = hf * 64, bhi = hf ? 127 : 64;
#pragma unroll 8
    for (int b = blo; b < bhi; ++b)
        acc += gs[b] * L2[b * OUT_CH + o];   // gs[b] is an LDS broadcast (free)
    part[hf][o] = acc;
    __syncthreads();
    if (tid < 128)
        out[(size_t)n * OUT_CH + tid] =
            part[0][tid] + part[1][tid] + R[(size_t)n * OUT_CH + tid] + bias[tid];
}

// ---------------------------------------------------------------------------
// Kernel C: out += adj @ P via MFMA bf16 -- ATOMIC-FREE rewrite.
// Old version K-split across 16 blocks -> 2.1M device-scope fp32 atomicAdds
// (16 colliding per output element, cross-XCD) -- suspected ~50 us of pure
// coherence-point serialization.
// New: grid 128 = 64 n-tiles (16 rows) x 2 o-halves (64 cols). Each block
// owns its full-K output tile; the 4 waves split K=1024 into 4 x 256 and
// accumulate in registers; partials reduce through padded LDS (no bank
// conflicts), then one coalesced read-modify-write of out. out was fully
// written by edge_out_kernel earlier in the same stream.
// A-frag: lane holds adj[(n0+col)][k=quad*8+j..+7] (fp32->bf16, 2x16B loads);
// B-frag: PT[o][k] bf16 16-B loads (exactly the B layout). D: row=quad*4+r.
// ---------------------------------------------------------------------------
__global__ void adjp_kernel(const float* __restrict__ adj,
                            const short* __restrict__ PT,
                            float* __restrict__ out) {
    int blk = blockIdx.x;
    int nb = blk & 63;          // n-tile: 16 rows
    int oh = blk >> 6;          // o-half: 64 cols
    int tid = threadIdx.x;
    int wave = tid >> 6;
    int lane = tid & 63;
    int quad = lane >> 4;
    int col  = lane & 15;
    int n0 = nb * 16;
    int o0 = oh * 64;

    f32x4 acc[4];
#pragma unroll
    for (int ot = 0; ot < 4; ++ot) acc[ot] = (f32x4){0.f, 0.f, 0.f, 0.f};

    int kbase = wave * 256;     // wave-level K-split, reduced in LDS below
#pragma unroll
    for (int ks = 0; ks < 8; ++ks) {
        int k = kbase + ks * 32 + quad * 8;
        const float* ap = adj + (size_t)(n0 + col) * NN + k;
        f32x4 a0 = *(const f32x4*)ap;
        f32x4 a1 = *(const f32x4*)(ap + 4);
        bf16x8 a;
#pragma unroll
        for (int j = 0; j < 4; ++j) { a[j] = f2bf(a0[j]); a[4 + j] = f2bf(a1[j]); }
#pragma unroll
        for (int ot = 0; ot < 4; ++ot) {
            int o = o0 + ot * 16 + col;
            bf16x8 b = *(const bf16x8*)(PT + (size_t)o * NN + k);
            acc[ot] = __builtin_amdgcn_mfma_f32_16x16x32_bf16(a, b, acc[ot], 0, 0, 0);
        }
    }

    // cross-wave K-reduction through LDS (pad 64->65: quads land on distinct banks)
    __shared__ float red[4][16][65];
#pragma unroll
    for (int ot = 0; ot < 4; ++ot)
#pragma unroll
        for (int r = 0; r < 4; ++r)
            red[wave][quad * 4 + r][ot * 16 + col] = acc[ot][r];
    __syncthreads();

    // 1024 tile elements / 256 threads = 4 each; coalesced += into out
#pragma unroll
    for (int i = tid; i < 16 * 64; i += 256) {
        int rr = i >> 6;
        int cc = i & 63;
        float v = red[0][rr][cc] + red[1][rr][cc] + red[2][rr][cc] + red[3][rr][cc];
        out[(size_t)(n0 + rr) * OUT_CH + o0 + cc] += v;
    }
}

extern "C" void kernel_launch(void* const* d_in, const int* in_sizes, int n_in,
                              void* d_out, int out_size, void* d_ws, size_t ws_size,
                              hipStream_t stream) {
    const float* node_mat    = (const float*)d_in[0];
    const float* adj         = (const float*)d_in[1];
    const float* edge_adj    = (const float*)d_in[2];
    const float* node_weight = (const float*)d_in[3];
    const float* edge_lay_1  = (const float*)d_in[4];
    const float* edge_lay_2  = (const float*)d_in[5];
    const float* root        = (const float*)d_in[6];
    const float* bias        = (const float*)d_in[7];
    float* out = (float*)d_out;

    short* PT = (short*)d_ws;                       // 128*1024 bf16 = 256 KB
    float* R  = (float*)((char*)d_ws + OUT_CH * NN * sizeof(short));  // 512 KB

    node_gemm_kernel<<<NN / 2, 256, 0, stream>>>(node_mat, node_weight, root, PT, R);
    edge_out_kernel<<<NN, 256, 0, stream>>>(edge_adj, adj, edge_lay_1, edge_lay_2,
                                            R, bias, out);
    adjp_kernel<<<128, 256, 0, stream>>>(adj, PT, out);
}